// Round 1
// baseline (635.070 us; speedup 1.0000x reference)
//
#include <hip/hip_runtime.h>
#include <cstdio>

// Problem constants: B=64, NN=17 (node + 16 neighbors), T=128, H=256.
// outputs [64,17,128,256] fp32 then A [64,17,128,128] fp32, concat in d_out.
//
// Refactor: S = qWk @ kv^T with We = Wq^T@Wb@Wk, qWk = node@We  (key GEMM eliminated).
// S-path in fp32 (softmax logits sigma~16: bf16 there is too lossy for A's threshold).
// V-path (V = kv@Wv^T, out = A@V) in bf16 MFMA (feeds only `outputs`, threshold 0.118).

typedef __bf16 bf16;
typedef __attribute__((ext_vector_type(8))) __bf16 bf16x8;
typedef __attribute__((ext_vector_type(4))) float floatx4;

#define MFMA_BF16 __builtin_amdgcn_mfma_f32_16x16x32_bf16

// kv[b,n,s,:] : n==0 -> node row, else neigh row
__device__ __forceinline__ const float* kv_row_ptr(const float* node, const float* neigh, int bn, int s) {
  int b = bn / 17, nn = bn % 17;
  return (nn == 0) ? node + ((size_t)b * 128 + s) * 256
                   : neigh + (((size_t)b * 16 + (nn - 1)) * 128 + s) * 256;
}

// ---------- K0a: Wc[m][h] = sum_i Wq[i][m] * Wb[i][h]  (Wq^T @ Wb) ----------
__global__ __launch_bounds__(256) void k_wc(const float* __restrict__ Wq, const float* __restrict__ Wb,
                                            float* __restrict__ Wc) {
  int m = blockIdx.x, h = threadIdx.x;
  float acc = 0.f;
  for (int k = 0; k < 256; ++k) acc = fmaf(Wq[k * 256 + m], Wb[k * 256 + h], acc);
  Wc[m * 256 + h] = acc;
}

// ---------- K0b: We[m][g] = sum_h Wc[m][h] * Wk[h][g] ----------
__global__ __launch_bounds__(256) void k_we(const float* __restrict__ Wc, const float* __restrict__ Wk,
                                            float* __restrict__ We) {
  int m = blockIdx.x, g = threadIdx.x;
  float acc = 0.f;
  for (int k = 0; k < 256; ++k) acc = fmaf(Wc[m * 256 + k], Wk[k * 256 + g], acc);
  We[m * 256 + g] = acc;
}

// ---------- K1: qWk[m][n] = sum_k node[m][k] * We[k][n]; M=8192,N=256,K=256, fp32 ----------
__global__ __launch_bounds__(256) void k_qwk(const float* __restrict__ X, const float* __restrict__ W,
                                             float* __restrict__ Y) {
  __shared__ float As[32][64];  // [k][m]
  __shared__ float Bs[32][64];  // [k][n]
  int tid = threadIdx.x;
  int m0 = blockIdx.x * 64, n0 = blockIdx.y * 64;
  int tx = tid & 15, ty = tid >> 4;
  float acc[4][4] = {};
  int r = tid >> 3, c4 = (tid & 7) * 4;
  int kr = tid >> 4, c4b = (tid & 15) * 4;
  for (int k0 = 0; k0 < 256; k0 += 32) {
#pragma unroll
    for (int p = 0; p < 2; ++p) {
      float4 v = *(const float4*)(X + (size_t)(m0 + r + p * 32) * 256 + k0 + c4);
      As[c4 + 0][r + p * 32] = v.x; As[c4 + 1][r + p * 32] = v.y;
      As[c4 + 2][r + p * 32] = v.z; As[c4 + 3][r + p * 32] = v.w;
    }
#pragma unroll
    for (int p = 0; p < 2; ++p) {
      float4 v = *(const float4*)(W + (size_t)(k0 + kr + p * 16) * 256 + n0 + c4b);
      *(float4*)&Bs[kr + p * 16][c4b] = v;
    }
    __syncthreads();
#pragma unroll 8
    for (int k = 0; k < 32; ++k) {
      float a[4], bb[4];
#pragma unroll
      for (int i = 0; i < 4; ++i) a[i] = As[k][ty * 4 + i];
#pragma unroll
      for (int j = 0; j < 4; ++j) bb[j] = Bs[k][tx * 4 + j];
#pragma unroll
      for (int i = 0; i < 4; ++i)
#pragma unroll
        for (int j = 0; j < 4; ++j) acc[i][j] = fmaf(a[i], bb[j], acc[i][j]);
    }
    __syncthreads();
  }
#pragma unroll
  for (int i = 0; i < 4; ++i) {
    float4 v = make_float4(acc[i][0], acc[i][1], acc[i][2], acc[i][3]);
    *(float4*)(Y + (size_t)(m0 + ty * 4 + i) * 256 + n0 + tx * 4) = v;
  }
}

// ---------- K2: V[r][h] = sum_g kv[r][g] * Wv[h][g], bf16 MFMA; M=139264,N=256,K=256 ----------
__global__ __launch_bounds__(256) void k_vgemm(const float* __restrict__ node, const float* __restrict__ neigh,
                                               const float* __restrict__ Wv, bf16* __restrict__ V) {
  __shared__ bf16 As[64][32];  // [m][k]
  __shared__ bf16 Bs[64][32];  // [n][k] (B[k][n] = Wv[n][k])
  int tid = threadIdx.x;
  int m0 = blockIdx.x * 64, n0 = blockIdx.y * 64;
  int wave = tid >> 6, lane = tid & 63, lrow = lane & 15, quad = lane >> 4;
  int bn = m0 >> 7, s0 = m0 & 127;
  const float* src = kv_row_ptr(node, neigh, bn, s0);  // rows m0..m0+63 are same bn
  floatx4 acc[4];
#pragma unroll
  for (int nt = 0; nt < 4; ++nt) acc[nt] = (floatx4)0.0f;
  int r = tid >> 3, c4 = (tid & 7) * 4;
  for (int k0 = 0; k0 < 256; k0 += 32) {
#pragma unroll
    for (int p = 0; p < 2; ++p) {
      float4 v = *(const float4*)(src + (size_t)(r + p * 32) * 256 + k0 + c4);
      bf16* d = &As[r + p * 32][c4];
      d[0] = (bf16)v.x; d[1] = (bf16)v.y; d[2] = (bf16)v.z; d[3] = (bf16)v.w;
      float4 w = *(const float4*)(Wv + (size_t)(n0 + r + p * 32) * 256 + k0 + c4);
      bf16* d2 = &Bs[r + p * 32][c4];
      d2[0] = (bf16)w.x; d2[1] = (bf16)w.y; d2[2] = (bf16)w.z; d2[3] = (bf16)w.w;
    }
    __syncthreads();
    bf16x8 af = *(const bf16x8*)&As[wave * 16 + lrow][quad * 8];
#pragma unroll
    for (int nt = 0; nt < 4; ++nt) {
      bf16x8 bfv = *(const bf16x8*)&Bs[nt * 16 + lrow][quad * 8];
      acc[nt] = MFMA_BF16(af, bfv, acc[nt], 0, 0, 0);
    }
    __syncthreads();
  }
#pragma unroll
  for (int nt = 0; nt < 4; ++nt)
#pragma unroll
    for (int rg = 0; rg < 4; ++rg)
      V[(size_t)(m0 + wave * 16 + quad * 4 + rg) * 256 + n0 + nt * 16 + lrow] = (bf16)acc[nt][rg];
}

// ---------- K3: per (b,n): S = qWk[b] @ kv^T + b[s], softmax over s -> A (fp32) ----------
__global__ __launch_bounds__(256) void k_attn(const float* __restrict__ qWk, const float* __restrict__ node,
                                              const float* __restrict__ neigh, const float* __restrict__ bvec,
                                              float* __restrict__ Aout) {
  __shared__ float Qs[32][128];  // [g][t]
  __shared__ float Ks[32][128];  // [g][s]
  int tid = threadIdx.x, tx = tid & 15, ty = tid >> 4;
  int bn = blockIdx.x;
  const float* Q = qWk + (size_t)(bn / 17) * 128 * 256;
  const float* K = kv_row_ptr(node, neigh, bn, 0);
  float acc[8][8] = {};
  int r = tid >> 3, c4 = (tid & 7) * 4;
  for (int g0 = 0; g0 < 256; g0 += 32) {
#pragma unroll
    for (int p = 0; p < 4; ++p) {
      int row = r + p * 32;
      float4 q4 = *(const float4*)(Q + (size_t)row * 256 + g0 + c4);
      float4 k4 = *(const float4*)(K + (size_t)row * 256 + g0 + c4);
      Qs[c4 + 0][row] = q4.x; Qs[c4 + 1][row] = q4.y; Qs[c4 + 2][row] = q4.z; Qs[c4 + 3][row] = q4.w;
      Ks[c4 + 0][row] = k4.x; Ks[c4 + 1][row] = k4.y; Ks[c4 + 2][row] = k4.z; Ks[c4 + 3][row] = k4.w;
    }
    __syncthreads();
#pragma unroll 4
    for (int g = 0; g < 32; ++g) {
      float a[8], bb[8];
#pragma unroll
      for (int i = 0; i < 8; ++i) a[i] = Qs[g][ty * 8 + i];
#pragma unroll
      for (int j = 0; j < 8; ++j) bb[j] = Ks[g][tx * 8 + j];
#pragma unroll
      for (int i = 0; i < 8; ++i)
#pragma unroll
        for (int j = 0; j < 8; ++j) acc[i][j] = fmaf(a[i], bb[j], acc[i][j]);
    }
    __syncthreads();
  }
  float bv[8];
#pragma unroll
  for (int j = 0; j < 8; ++j) bv[j] = bvec[tx * 8 + j];
  float* out = Aout + (size_t)bn * 128 * 128;
#pragma unroll
  for (int i = 0; i < 8; ++i) {
    float mx = -3.402823466e+38f;
#pragma unroll
    for (int j = 0; j < 8; ++j) { acc[i][j] += bv[j]; mx = fmaxf(mx, acc[i][j]); }
#pragma unroll
    for (int off = 1; off < 16; off <<= 1) mx = fmaxf(mx, __shfl_xor(mx, off, 64));
    float s = 0.f;
#pragma unroll
    for (int j = 0; j < 8; ++j) { float e = __expf(acc[i][j] - mx); acc[i][j] = e; s += e; }
#pragma unroll
    for (int off = 1; off < 16; off <<= 1) s += __shfl_xor(s, off, 64);
    float inv = 1.f / s;
    int row = ty * 8 + i;
    float4 v0 = make_float4(acc[i][0] * inv, acc[i][1] * inv, acc[i][2] * inv, acc[i][3] * inv);
    float4 v1 = make_float4(acc[i][4] * inv, acc[i][5] * inv, acc[i][6] * inv, acc[i][7] * inv);
    *(float4*)(out + (size_t)row * 128 + tx * 8) = v0;
    *(float4*)(out + (size_t)row * 128 + tx * 8 + 4) = v1;
  }
}

// ---------- K4: out = A @ V, bf16 MFMA; per-bn K=128 ----------
__global__ __launch_bounds__(256) void k_out(const float* __restrict__ Amat, const bf16* __restrict__ V,
                                             float* __restrict__ Out) {
  __shared__ bf16 As[64][32];  // [t][s]
  __shared__ bf16 Bs[64][32];  // [h][s] (B[k=s][n=h] = V[s][h])
  int tid = threadIdx.x;
  int m0 = blockIdx.x * 64, n0 = blockIdx.y * 64;
  int wave = tid >> 6, lane = tid & 63, lrow = lane & 15, quad = lane >> 4;
  int bn = m0 >> 7, t0 = m0 & 127;
  const float* Ab = Amat + (size_t)bn * 128 * 128;
  const bf16* Vb = V + (size_t)bn * 128 * 256;
  floatx4 acc[4];
#pragma unroll
  for (int nt = 0; nt < 4; ++nt) acc[nt] = (floatx4)0.0f;
  int r = tid >> 3, c4 = (tid & 7) * 4, c8 = (tid & 7) * 8;
  for (int k0 = 0; k0 < 128; k0 += 32) {
#pragma unroll
    for (int p = 0; p < 2; ++p) {
      float4 v = *(const float4*)(Ab + (size_t)(t0 + r + p * 32) * 128 + k0 + c4);
      bf16* d = &As[r + p * 32][c4];
      d[0] = (bf16)v.x; d[1] = (bf16)v.y; d[2] = (bf16)v.z; d[3] = (bf16)v.w;
    }
    {
      bf16x8 v = *(const bf16x8*)(Vb + (size_t)(k0 + r) * 256 + n0 + c8);
#pragma unroll
      for (int u = 0; u < 8; ++u) Bs[c8 + u][r] = v[u];
    }
    __syncthreads();
    bf16x8 af = *(const bf16x8*)&As[wave * 16 + lrow][quad * 8];
#pragma unroll
    for (int nt = 0; nt < 4; ++nt) {
      bf16x8 bfv = *(const bf16x8*)&Bs[nt * 16 + lrow][quad * 8];
      acc[nt] = MFMA_BF16(af, bfv, acc[nt], 0, 0, 0);
    }
    __syncthreads();
  }
#pragma unroll
  for (int nt = 0; nt < 4; ++nt)
#pragma unroll
    for (int rg = 0; rg < 4; ++rg)
      Out[(size_t)(m0 + wave * 16 + quad * 4 + rg) * 256 + n0 + nt * 16 + lrow] = acc[nt][rg];
}

extern "C" void kernel_launch(void* const* d_in, const int* in_sizes, int n_in,
                              void* d_out, int out_size, void* d_ws, size_t ws_size,
                              hipStream_t stream) {
  const float* node  = (const float*)d_in[0];
  const float* neigh = (const float*)d_in[1];
  // d_in[2] = neighbors_number (int, ==16) — shape-determined, unused
  const float* Wq = (const float*)d_in[3];
  const float* Wk = (const float*)d_in[4];
  const float* Wv = (const float*)d_in[5];
  const float* Wb = (const float*)d_in[6];
  const float* bv = (const float*)d_in[7];

  float* out  = (float*)d_out;                       // outputs: 64*17*128*256
  float* Aout = out + (size_t)64 * 17 * 128 * 256;   // A: 64*17*128*128

  // workspace: Wc(64K f32) | We(64K f32) | qWk(2M f32) | V(35.65M bf16) = 80,216,064 B
  size_t need = (size_t)(65536 + 65536 + 2097152) * 4 + (size_t)35651584 * 2;
  if (ws_size < need) { fprintf(stderr, "ws too small: %zu < %zu\n", ws_size, need); return; }
  float* wsf = (float*)d_ws;
  float* Wc  = wsf;
  float* We  = wsf + 65536;
  float* qWk = wsf + 131072;
  bf16*  V   = (bf16*)(wsf + 131072 + 2097152);

  k_wc<<<256, 256, 0, stream>>>(Wq, Wb, Wc);
  k_we<<<256, 256, 0, stream>>>(Wc, Wk, We);
  k_qwk<<<dim3(128, 4), 256, 0, stream>>>(node, We, qWk);
  k_vgemm<<<dim3(2176, 4), 256, 0, stream>>>(node, neigh, Wv, V);
  k_attn<<<1088, 256, 0, stream>>>(qWk, node, neigh, bv, Aout);
  k_out<<<dim3(2176, 4), 256, 0, stream>>>(Aout, V, out);
}

// Round 2
// 527.395 us; speedup vs baseline: 1.2042x; 1.2042x over previous
//
#include <hip/hip_runtime.h>
#include <cstdio>

// B=64, NN=17, T=128, H=256.
// d_out = outputs [64,17,128,256] fp32 ++ A [64,17,128,128] fp32.
//
// Refactor: We = Wq^T@Wb@Wk; qWk = node@We; S = qWk@kv^T + b[s]; A = softmax_s(S);
// out = A @ (kv@Wv^T).
// Round 2: QK^T via bf16 MFMA with hi/lo split (3 terms) for fp32-grade logits;
// softmax + PV fused in one kernel (k_out eliminated, A never re-read from HBM).

typedef __bf16 bf16;
typedef __attribute__((ext_vector_type(8))) __bf16 bf16x8;
typedef __attribute__((ext_vector_type(4))) float floatx4;

#define MFMA_BF16 __builtin_amdgcn_mfma_f32_16x16x32_bf16

__device__ __forceinline__ const float* kv_row_ptr(const float* node, const float* neigh, int bn, int s) {
  int b = bn / 17, nn = bn % 17;
  return (nn == 0) ? node + ((size_t)b * 128 + s) * 256
                   : neigh + (((size_t)b * 16 + (nn - 1)) * 128 + s) * 256;
}

// ---------- K0a: Wc = Wq^T @ Wb ----------
__global__ __launch_bounds__(256) void k_wc(const float* __restrict__ Wq, const float* __restrict__ Wb,
                                            float* __restrict__ Wc) {
  int m = blockIdx.x, h = threadIdx.x;
  float acc = 0.f;
  for (int k = 0; k < 256; ++k) acc = fmaf(Wq[k * 256 + m], Wb[k * 256 + h], acc);
  Wc[m * 256 + h] = acc;
}

// ---------- K0b: We = Wc @ Wk ----------
__global__ __launch_bounds__(256) void k_we(const float* __restrict__ Wc, const float* __restrict__ Wk,
                                            float* __restrict__ We) {
  int m = blockIdx.x, g = threadIdx.x;
  float acc = 0.f;
  for (int k = 0; k < 256; ++k) acc = fmaf(Wc[m * 256 + k], Wk[k * 256 + g], acc);
  We[m * 256 + g] = acc;
}

// ---------- K1: qWk = node @ We; M=8192,N=256,K=256 fp32 ----------
__global__ __launch_bounds__(256) void k_qwk(const float* __restrict__ X, const float* __restrict__ W,
                                             float* __restrict__ Y) {
  __shared__ float As[32][64];
  __shared__ float Bs[32][64];
  int tid = threadIdx.x;
  int m0 = blockIdx.x * 64, n0 = blockIdx.y * 64;
  int tx = tid & 15, ty = tid >> 4;
  float acc[4][4] = {};
  int r = tid >> 3, c4 = (tid & 7) * 4;
  int kr = tid >> 4, c4b = (tid & 15) * 4;
  for (int k0 = 0; k0 < 256; k0 += 32) {
#pragma unroll
    for (int p = 0; p < 2; ++p) {
      float4 v = *(const float4*)(X + (size_t)(m0 + r + p * 32) * 256 + k0 + c4);
      As[c4 + 0][r + p * 32] = v.x; As[c4 + 1][r + p * 32] = v.y;
      As[c4 + 2][r + p * 32] = v.z; As[c4 + 3][r + p * 32] = v.w;
    }
#pragma unroll
    for (int p = 0; p < 2; ++p) {
      float4 v = *(const float4*)(W + (size_t)(k0 + kr + p * 16) * 256 + n0 + c4b);
      *(float4*)&Bs[kr + p * 16][c4b] = v;
    }
    __syncthreads();
#pragma unroll 8
    for (int k = 0; k < 32; ++k) {
      float a[4], bb[4];
#pragma unroll
      for (int i = 0; i < 4; ++i) a[i] = As[k][ty * 4 + i];
#pragma unroll
      for (int j = 0; j < 4; ++j) bb[j] = Bs[k][tx * 4 + j];
#pragma unroll
      for (int i = 0; i < 4; ++i)
#pragma unroll
        for (int j = 0; j < 4; ++j) acc[i][j] = fmaf(a[i], bb[j], acc[i][j]);
    }
    __syncthreads();
  }
#pragma unroll
  for (int i = 0; i < 4; ++i) {
    float4 v = make_float4(acc[i][0], acc[i][1], acc[i][2], acc[i][3]);
    *(float4*)(Y + (size_t)(m0 + ty * 4 + i) * 256 + n0 + tx * 4) = v;
  }
}

// ---------- K2: V = kv @ Wv^T, bf16 MFMA ----------
__global__ __launch_bounds__(256) void k_vgemm(const float* __restrict__ node, const float* __restrict__ neigh,
                                               const float* __restrict__ Wv, bf16* __restrict__ V) {
  __shared__ bf16 As[64][32];
  __shared__ bf16 Bs[64][32];
  int tid = threadIdx.x;
  int m0 = blockIdx.x * 64, n0 = blockIdx.y * 64;
  int wave = tid >> 6, lane = tid & 63, lrow = lane & 15, quad = lane >> 4;
  int bn = m0 >> 7, s0 = m0 & 127;
  const float* src = kv_row_ptr(node, neigh, bn, s0);
  floatx4 acc[4];
#pragma unroll
  for (int nt = 0; nt < 4; ++nt) acc[nt] = (floatx4)0.0f;
  int r = tid >> 3, c4 = (tid & 7) * 4;
  for (int k0 = 0; k0 < 256; k0 += 32) {
#pragma unroll
    for (int p = 0; p < 2; ++p) {
      float4 v = *(const float4*)(src + (size_t)(r + p * 32) * 256 + k0 + c4);
      bf16* d = &As[r + p * 32][c4];
      d[0] = (bf16)v.x; d[1] = (bf16)v.y; d[2] = (bf16)v.z; d[3] = (bf16)v.w;
      float4 w = *(const float4*)(Wv + (size_t)(n0 + r + p * 32) * 256 + k0 + c4);
      bf16* d2 = &Bs[r + p * 32][c4];
      d2[0] = (bf16)w.x; d2[1] = (bf16)w.y; d2[2] = (bf16)w.z; d2[3] = (bf16)w.w;
    }
    __syncthreads();
    bf16x8 af = *(const bf16x8*)&As[wave * 16 + lrow][quad * 8];
#pragma unroll
    for (int nt = 0; nt < 4; ++nt) {
      bf16x8 bfv = *(const bf16x8*)&Bs[nt * 16 + lrow][quad * 8];
      acc[nt] = MFMA_BF16(af, bfv, acc[nt], 0, 0, 0);
    }
    __syncthreads();
  }
#pragma unroll
  for (int nt = 0; nt < 4; ++nt)
#pragma unroll
    for (int rg = 0; rg < 4; ++rg)
      V[(size_t)(m0 + wave * 16 + quad * 4 + rg) * 256 + n0 + nt * 16 + lrow] = (bf16)acc[nt][rg];
}

// ---------- K3 fused: S=qWk@kv^T (hi/lo bf16 MFMA) + bias + softmax -> A; out = A@V ----------
// one block per bn; 256 threads = 4 waves; wave w owns rows w*32..w*32+31.
#define QKS 40   // padded k-stride (bf16) for Q/K staging buffers
#define ABS 136  // padded s-stride (bf16) for A / Vt buffers
__global__ __launch_bounds__(256) void k_fused(const float* __restrict__ qWk, const float* __restrict__ node,
                                               const float* __restrict__ neigh, const float* __restrict__ bvec,
                                               const bf16* __restrict__ V,
                                               float* __restrict__ Aout, float* __restrict__ Out) {
  __shared__ __align__(16) char smem[52224];
  bf16* Qhi = (bf16*)smem;               // [128][QKS]
  bf16* Qlo = (bf16*)(smem + 10240);
  bf16* Khi = (bf16*)(smem + 20480);
  bf16* Klo = (bf16*)(smem + 30720);
  bf16* Ab  = (bf16*)smem;               // [128][ABS]  (phase 2, aliases phase-1 bufs)
  bf16* Vt  = (bf16*)(smem + 34816);     // [64][ABS]

  int tid = threadIdx.x;
  int w = tid >> 6, lane = tid & 63, lrow = lane & 15, quad = lane >> 4;
  int bn = blockIdx.x;
  const float* Q = qWk + (size_t)(bn / 17) * 128 * 256;
  const float* K = kv_row_ptr(node, neigh, bn, 0);

  int srow = tid >> 1;            // staging row 0..127
  int skb = (tid & 1) * 16;       // staging k base 0 or 16

  floatx4 acc[2][8];
#pragma unroll
  for (int rt = 0; rt < 2; ++rt)
#pragma unroll
    for (int ct = 0; ct < 8; ++ct) acc[rt][ct] = (floatx4)0.0f;

  // ---- phase 1: S = Q @ K^T via 3-term hi/lo split ----
  for (int k0 = 0; k0 < 256; k0 += 32) {
#pragma unroll
    for (int half = 0; half < 2; ++half) {  // two 8-float chunks per thread per matrix
      const float* qp = Q + (size_t)srow * 256 + k0 + skb + half * 8;
      const float* kp = K + (size_t)srow * 256 + k0 + skb + half * 8;
      float4 q0 = *(const float4*)qp, q1 = *(const float4*)(qp + 4);
      float4 kk0 = *(const float4*)kp, kk1 = *(const float4*)(kp + 4);
      float qf[8] = {q0.x, q0.y, q0.z, q0.w, q1.x, q1.y, q1.z, q1.w};
      float kf[8] = {kk0.x, kk0.y, kk0.z, kk0.w, kk1.x, kk1.y, kk1.z, kk1.w};
      bf16x8 qh, ql, kh, kl;
#pragma unroll
      for (int u = 0; u < 8; ++u) {
        bf16 h = (bf16)qf[u]; qh[u] = h; ql[u] = (bf16)(qf[u] - (float)h);
        bf16 h2 = (bf16)kf[u]; kh[u] = h2; kl[u] = (bf16)(kf[u] - (float)h2);
      }
      int off = srow * QKS + skb + half * 8;
      *(bf16x8*)&Qhi[off] = qh; *(bf16x8*)&Qlo[off] = ql;
      *(bf16x8*)&Khi[off] = kh; *(bf16x8*)&Klo[off] = kl;
    }
    __syncthreads();
    bf16x8 ah[2], al[2];
#pragma unroll
    for (int rt = 0; rt < 2; ++rt) {
      int off = (w * 32 + rt * 16 + lrow) * QKS + quad * 8;
      ah[rt] = *(const bf16x8*)&Qhi[off];
      al[rt] = *(const bf16x8*)&Qlo[off];
    }
#pragma unroll
    for (int ct = 0; ct < 8; ++ct) {
      int off = (ct * 16 + lrow) * QKS + quad * 8;
      bf16x8 bh = *(const bf16x8*)&Khi[off];
      bf16x8 bl = *(const bf16x8*)&Klo[off];
#pragma unroll
      for (int rt = 0; rt < 2; ++rt) {
        acc[rt][ct] = MFMA_BF16(ah[rt], bh, acc[rt][ct], 0, 0, 0);
        acc[rt][ct] = MFMA_BF16(al[rt], bh, acc[rt][ct], 0, 0, 0);
        acc[rt][ct] = MFMA_BF16(ah[rt], bl, acc[rt][ct], 0, 0, 0);
      }
    }
    __syncthreads();
  }

  // ---- softmax over s (per row), in registers ----
  float bvv[8];
#pragma unroll
  for (int ct = 0; ct < 8; ++ct) bvv[ct] = bvec[ct * 16 + lrow];
#pragma unroll
  for (int rt = 0; rt < 2; ++rt)
#pragma unroll
    for (int r = 0; r < 4; ++r) {
      float mx = -3.402823466e+38f;
#pragma unroll
      for (int ct = 0; ct < 8; ++ct) {
        float v = acc[rt][ct][r] + bvv[ct];
        acc[rt][ct][r] = v;
        mx = fmaxf(mx, v);
      }
#pragma unroll
      for (int off = 1; off < 16; off <<= 1) mx = fmaxf(mx, __shfl_xor(mx, off, 64));
      float s = 0.f;
#pragma unroll
      for (int ct = 0; ct < 8; ++ct) {
        float e = __expf(acc[rt][ct][r] - mx);
        acc[rt][ct][r] = e;
        s += e;
      }
#pragma unroll
      for (int off = 1; off < 16; off <<= 1) s += __shfl_xor(s, off, 64);
      float inv = 1.f / s;
#pragma unroll
      for (int ct = 0; ct < 8; ++ct) acc[rt][ct][r] *= inv;
    }

  // ---- write A (global fp32 output) + Ab (LDS bf16, A-operand layout for PV) ----
  float* Ag = Aout + (size_t)bn * 128 * 128;
#pragma unroll
  for (int rt = 0; rt < 2; ++rt)
#pragma unroll
    for (int r = 0; r < 4; ++r) {
      int row = w * 32 + rt * 16 + quad * 4 + r;
#pragma unroll
      for (int ct = 0; ct < 8; ++ct) {
        int s = ct * 16 + lrow;
        float v = acc[rt][ct][r];
        Ag[(size_t)row * 128 + s] = v;
        Ab[row * ABS + s] = (bf16)v;
      }
    }

  // ---- phase 2: out = A @ V, h in 4 chunks of 64 ----
  const bf16* Vb = V + (size_t)bn * 128 * 256;
  float* Ob = Out + (size_t)bn * 128 * 256;
  int vs = tid & 127, vh = tid >> 7;  // staging: s row, h-octet selector
  for (int h0 = 0; h0 < 256; h0 += 64) {
#pragma unroll
    for (int it = 0; it < 4; ++it) {
      int idx8 = it * 2 + vh;  // 0..7 -> h sub-block of 8
      bf16x8 v = *(const bf16x8*)&Vb[(size_t)vs * 256 + h0 + idx8 * 8];
#pragma unroll
      for (int u = 0; u < 8; ++u) Vt[(idx8 * 8 + u) * ABS + vs] = v[u];
    }
    __syncthreads();
    floatx4 pacc[2][4];
#pragma unroll
    for (int rt = 0; rt < 2; ++rt)
#pragma unroll
      for (int ct = 0; ct < 4; ++ct) pacc[rt][ct] = (floatx4)0.0f;
#pragma unroll
    for (int s0 = 0; s0 < 128; s0 += 32) {
      bf16x8 af[2];
#pragma unroll
      for (int rt = 0; rt < 2; ++rt)
        af[rt] = *(const bf16x8*)&Ab[(w * 32 + rt * 16 + lrow) * ABS + s0 + quad * 8];
#pragma unroll
      for (int ct = 0; ct < 4; ++ct) {
        bf16x8 bv8 = *(const bf16x8*)&Vt[(ct * 16 + lrow) * ABS + s0 + quad * 8];
#pragma unroll
        for (int rt = 0; rt < 2; ++rt)
          pacc[rt][ct] = MFMA_BF16(af[rt], bv8, pacc[rt][ct], 0, 0, 0);
      }
    }
#pragma unroll
    for (int rt = 0; rt < 2; ++rt)
#pragma unroll
      for (int ct = 0; ct < 4; ++ct)
#pragma unroll
        for (int r = 0; r < 4; ++r) {
          int row = w * 32 + rt * 16 + quad * 4 + r;
          Ob[(size_t)row * 256 + h0 + ct * 16 + lrow] = pacc[rt][ct][r];
        }
    __syncthreads();
  }
}

extern "C" void kernel_launch(void* const* d_in, const int* in_sizes, int n_in,
                              void* d_out, int out_size, void* d_ws, size_t ws_size,
                              hipStream_t stream) {
  const float* node  = (const float*)d_in[0];
  const float* neigh = (const float*)d_in[1];
  const float* Wq = (const float*)d_in[3];
  const float* Wk = (const float*)d_in[4];
  const float* Wv = (const float*)d_in[5];
  const float* Wb = (const float*)d_in[6];
  const float* bv = (const float*)d_in[7];

  float* out  = (float*)d_out;
  float* Aout = out + (size_t)64 * 17 * 128 * 256;

  size_t need = (size_t)(65536 + 65536 + 2097152) * 4 + (size_t)35651584 * 2;
  if (ws_size < need) { fprintf(stderr, "ws too small: %zu < %zu\n", ws_size, need); return; }
  float* wsf = (float*)d_ws;
  float* Wc  = wsf;
  float* We  = wsf + 65536;
  float* qWk = wsf + 131072;
  bf16*  V   = (bf16*)(wsf + 131072 + 2097152);

  k_wc<<<256, 256, 0, stream>>>(Wq, Wb, Wc);
  k_we<<<256, 256, 0, stream>>>(Wc, Wk, We);
  k_qwk<<<dim3(128, 4), 256, 0, stream>>>(node, We, qWk);
  k_vgemm<<<dim3(2176, 4), 256, 0, stream>>>(node, neigh, Wv, V);
  k_fused<<<1088, 256, 0, stream>>>(qWk, node, neigh, bv, V, Aout, out);
}